// Round 7
// baseline (99.064 us; speedup 1.0000x reference)
//
#include <hip/hip_runtime.h>
#include <hip/hip_bf16.h>

// SelfAttention: B=2, S=4096, E=512, D=64, fp32 in/out.
// R7 = R5 (verified) + 64-key attn iterations (2 independent 32-key score
// chains -> 2x ILP), using ONLY the R1-proven shfl_xor cross-lane ops.
// No permlane anywhere (R2/R6 failed identically with it; banned pending
// isolated verification). proj/split/merge unchanged from R5.

typedef float  f32x16 __attribute__((ext_vector_type(16)));
typedef short  v8bf   __attribute__((ext_vector_type(8)));
typedef int    v4i    __attribute__((ext_vector_type(4)));

#define MFMA32(a, b, c) __builtin_amdgcn_mfma_f32_32x32x16_bf16((a), (b), (c), 0, 0, 0)

union Frag { v4i i4; v8bf b8; unsigned u[4]; };

__device__ __forceinline__ unsigned short f2bf(float x) {  // RNE fp32->bf16
    unsigned u = __float_as_uint(x);
    return (unsigned short)((u + 0x7fffu + ((u >> 16) & 1u)) >> 16);
}
__device__ __forceinline__ float bf2f(unsigned short h) {
    return __uint_as_float(((unsigned)h) << 16);
}
__device__ __forceinline__ unsigned cvt_pk_bf16(float a, float b) {
    unsigned r;
    asm("v_cvt_pk_bf16_f32 %0, %1, %2" : "=v"(r) : "v"(a), "v"(b));
    return r;
}

// ---------------- split kernels: fp32 -> (hi, lo) bf16 ----------------

__global__ __launch_bounds__(256) void split_kernel(
    const float* __restrict__ src, unsigned short* __restrict__ hi,
    unsigned short* __restrict__ lo, int n4)
{
    int i = blockIdx.x * 256 + threadIdx.x;
    const int stride = gridDim.x * 256;
    for (; i < n4; i += stride) {
        float4 v = reinterpret_cast<const float4*>(src)[i];
        unsigned short h0 = f2bf(v.x), h1 = f2bf(v.y), h2 = f2bf(v.z), h3 = f2bf(v.w);
        unsigned short l0 = f2bf(v.x - bf2f(h0)), l1 = f2bf(v.y - bf2f(h1));
        unsigned short l2 = f2bf(v.z - bf2f(h2)), l3 = f2bf(v.w - bf2f(h3));
        reinterpret_cast<uint2*>(hi)[i] =
            make_uint2((unsigned)h0 | ((unsigned)h1 << 16), (unsigned)h2 | ((unsigned)h3 << 16));
        reinterpret_cast<uint2*>(lo)[i] =
            make_uint2((unsigned)l0 | ((unsigned)l1 << 16), (unsigned)l2 | ((unsigned)l3 << 16));
    }
}

__global__ __launch_bounds__(256) void splitW_kernel(
    const float* __restrict__ wq, const float* __restrict__ wk, const float* __restrict__ wv,
    unsigned short* __restrict__ hi, unsigned short* __restrict__ lo)
{
    int i = blockIdx.x * 256 + threadIdx.x;  // exactly 24576 threads
    int e = i * 4;
    const float* src = (e < 32768) ? wq : (e < 65536) ? wk : wv;
    int off = e & 32767;
    float4 v = *reinterpret_cast<const float4*>(src + off);
    unsigned short h0 = f2bf(v.x), h1 = f2bf(v.y), h2 = f2bf(v.z), h3 = f2bf(v.w);
    unsigned short l0 = f2bf(v.x - bf2f(h0)), l1 = f2bf(v.y - bf2f(h1));
    unsigned short l2 = f2bf(v.z - bf2f(h2)), l3 = f2bf(v.w - bf2f(h3));
    reinterpret_cast<uint2*>(hi)[i] =
        make_uint2((unsigned)h0 | ((unsigned)h1 << 16), (unsigned)h2 | ((unsigned)h3 << 16));
    reinterpret_cast<uint2*>(lo)[i] =
        make_uint2((unsigned)l0 | ((unsigned)l1 << 16), (unsigned)l2 | ((unsigned)l3 << 16));
}

// ---------------- projection (unchanged from R5) ----------------

__global__ __launch_bounds__(64, 1) void proj_kernel(
    const unsigned short* __restrict__ Xhi, const unsigned short* __restrict__ Xlo,
    const unsigned short* __restrict__ Whi, const unsigned short* __restrict__ Wlo,
    unsigned short* __restrict__ Qhi, unsigned short* __restrict__ Qlo,
    unsigned short* __restrict__ Khi, unsigned short* __restrict__ Klo,
    unsigned short* __restrict__ VT)
{
    __shared__ float t[32][33];
    const int l = threadIdx.x, h = l >> 5, r32 = l & 31;
    const int row0 = blockIdx.x * 32;
    const int g2 = blockIdx.y;   // 0..5
    const int g  = g2 >> 1;      // 0=Q, 1=K, 2=V
    const int ct = g2 & 1;       // 32-column group

    f32x16 a0;
#pragma unroll
    for (int r = 0; r < 16; ++r) a0[r] = 0.f;

    for (int kc = 0; kc < 32; ++kc) {
        const int k0 = kc * 16 + 8 * h;
        Frag xh, xl, b0h;
        const int xo = (row0 + r32) * 512 + k0;
        const int w0 = (g * 64 + ct * 32 + r32) * 512 + k0;
        xh.i4  = *reinterpret_cast<const v4i*>(Xhi + xo);
        b0h.i4 = *reinterpret_cast<const v4i*>(Whi + w0);
        a0 = MFMA32(xh.b8, b0h.b8, a0);
        if (g < 2) {
            Frag b0l;
            xl.i4  = *reinterpret_cast<const v4i*>(Xlo + xo);
            b0l.i4 = *reinterpret_cast<const v4i*>(Wlo + w0);
            a0 = MFMA32(xh.b8, b0l.b8, a0);
            a0 = MFMA32(xl.b8, b0h.b8, a0);
        }
    }

    if (g == 2) {
        const int b  = row0 >> 12;
        const int s0 = row0 & 4095;
        const int v = ct * 32 + r32;
#pragma unroll
        for (int u = 0; u < 4; ++u) {
            const int srow = s0 + 8 * u + 4 * h;
            unsigned p0 = (unsigned)f2bf(a0[4 * u])     | ((unsigned)f2bf(a0[4 * u + 1]) << 16);
            unsigned p1 = (unsigned)f2bf(a0[4 * u + 2]) | ((unsigned)f2bf(a0[4 * u + 3]) << 16);
            *reinterpret_cast<uint2*>(VT + (b * 64 + v) * 4096 + srow) = make_uint2(p0, p1);
        }
    } else {
        unsigned short* Oh = g ? Khi : Qhi;
        unsigned short* Ol = g ? Klo : Qlo;
#pragma unroll
        for (int u = 0; u < 16; ++u)
            t[(u & 3) + 8 * (u >> 2) + 4 * h][r32] = a0[u];
        __syncthreads();
        unsigned wh[8], wl[8];
#pragma unroll
        for (int j = 0; j < 8; ++j) {
            float x0 = t[r32][16 * h + 2 * j];
            float x1 = t[r32][16 * h + 2 * j + 1];
            unsigned short h0 = f2bf(x0), h1 = f2bf(x1);
            unsigned short l0 = f2bf(x0 - bf2f(h0)), l1 = f2bf(x1 - bf2f(h1));
            wh[j] = (unsigned)h0 | ((unsigned)h1 << 16);
            wl[j] = (unsigned)l0 | ((unsigned)l1 << 16);
        }
        const int off = (row0 + r32) * 64 + ct * 32 + 16 * h;
        *reinterpret_cast<uint4*>(Oh + off)     = make_uint4(wh[0], wh[1], wh[2], wh[3]);
        *reinterpret_cast<uint4*>(Oh + off + 8) = make_uint4(wh[4], wh[5], wh[6], wh[7]);
        *reinterpret_cast<uint4*>(Ol + off)     = make_uint4(wl[0], wl[1], wl[2], wl[3]);
        *reinterpret_cast<uint4*>(Ol + off + 8) = make_uint4(wl[4], wl[5], wl[6], wl[7]);
    }
}

// ---------------- flash attention: 64-key iterations, shfl-only ----------

__global__ __launch_bounds__(512, 2) void attn_kernel(
    const unsigned short* __restrict__ Qhi, const unsigned short* __restrict__ Qlo,
    const unsigned short* __restrict__ Khi, const unsigned short* __restrict__ Klo,
    const unsigned short* __restrict__ VT,
    float* __restrict__ Opart, float* __restrict__ ml)
{
    __shared__ float sO[8][32][68];
    __shared__ float sm[8][32];
    __shared__ float sl[8][32];

    const int tid = threadIdx.x;
    const int w = tid >> 6;
    const int l = tid & 63;
    const int h = l >> 5;
    const int q = l & 31;
    const int b  = blockIdx.x >> 7;
    const int q0 = (blockIdx.x & 127) * 32;
    const int half = blockIdx.y;

    Frag qh[4], ql[4];
#pragma unroll
    for (int dc = 0; dc < 4; ++dc) {
        const int o = (b * 4096 + q0 + q) * 64 + dc * 16 + 8 * h;
        qh[dc].i4 = *reinterpret_cast<const v4i*>(Qhi + o);
        ql[dc].i4 = *reinterpret_cast<const v4i*>(Qlo + o);
    }

    f32x16 o0, o1;
#pragma unroll
    for (int r = 0; r < 16; ++r) { o0[r] = 0.f; o1[r] = 0.f; }
    float m_run = -1e30f, l_run = 0.f;

    for (int it = 0; it < 4; ++it) {
        const int keyA = half * 2048 + (it * 16 + w) * 32;
        const int keyB = keyA + 256;

        // --- two independent score chains (A,B), hi/lo split
        f32x16 sA, sB;
#pragma unroll
        for (int r = 0; r < 16; ++r) { sA[r] = 0.f; sB[r] = 0.f; }
#pragma unroll
        for (int dc = 0; dc < 4; ++dc) {
            Frag kha, kla, khb, klb;
            const int koA = (b * 4096 + keyA + q) * 64 + dc * 16 + 8 * h;
            const int koB = (b * 4096 + keyB + q) * 64 + dc * 16 + 8 * h;
            kha.i4 = *reinterpret_cast<const v4i*>(Khi + koA);
            kla.i4 = *reinterpret_cast<const v4i*>(Klo + koA);
            khb.i4 = *reinterpret_cast<const v4i*>(Khi + koB);
            klb.i4 = *reinterpret_cast<const v4i*>(Klo + koB);
            sA = MFMA32(kha.b8, qh[dc].b8, sA);
            sB = MFMA32(khb.b8, qh[dc].b8, sB);
            sA = MFMA32(kha.b8, ql[dc].b8, sA);
            sB = MFMA32(khb.b8, ql[dc].b8, sB);
            sA = MFMA32(kla.b8, qh[dc].b8, sA);
            sB = MFMA32(klb.b8, qh[dc].b8, sB);
        }

        // --- joint softmax over 64 keys (base 2; logits = 8*score)
        const float cc = 11.541560327111707f;  // 8 * log2(e)
        float s2[32];
#pragma unroll
        for (int r = 0; r < 16; ++r) { s2[r] = sA[r] * cc; s2[16 + r] = sB[r] * cc; }
        float mb;
        {
            float t[8];
#pragma unroll
            for (int jj = 0; jj < 8; ++jj)
                t[jj] = fmaxf(fmaxf(s2[4 * jj], s2[4 * jj + 1]),
                              fmaxf(s2[4 * jj + 2], s2[4 * jj + 3]));
            float u0 = fmaxf(fmaxf(t[0], t[1]), fmaxf(t[2], t[3]));
            float u1 = fmaxf(fmaxf(t[4], t[5]), fmaxf(t[6], t[7]));
            mb = fmaxf(u0, u1);
        }
        mb = fmaxf(mb, __shfl_xor(mb, 32));

        const float m_new = fmaxf(m_run, mb);
        const float f = exp2f(m_run - m_new);
        float p[32];
        float ps0 = 0.f, ps1 = 0.f, ps2 = 0.f, ps3 = 0.f;
#pragma unroll
        for (int r = 0; r < 32; r += 4) {
            p[r]     = exp2f(s2[r]     - m_new); ps0 += p[r];
            p[r + 1] = exp2f(s2[r + 1] - m_new); ps1 += p[r + 1];
            p[r + 2] = exp2f(s2[r + 2] - m_new); ps2 += p[r + 2];
            p[r + 3] = exp2f(s2[r + 3] - m_new); ps3 += p[r + 3];
        }
        float ps = (ps0 + ps1) + (ps2 + ps3);
        ps += __shfl_xor(ps, 32);
        l_run = l_run * f + ps;
        m_run = m_new;
#pragma unroll
        for (int r = 0; r < 16; ++r) { o0[r] *= f; o1[r] *= f; }

        // --- P (C layout, k = (r&3)+8*(r>>2)+4h) -> bf16 B-frags, per tile
        unsigned U[16];
#pragma unroll
        for (int j = 0; j < 8; ++j) {
            U[j]     = cvt_pk_bf16(p[2 * j],      p[2 * j + 1]);
            U[8 + j] = cvt_pk_bf16(p[16 + 2 * j], p[16 + 2 * j + 1]);
        }
        unsigned tA0 = h ? U[0]  : U[2];
        unsigned tA1 = h ? U[1]  : U[3];
        unsigned tA2 = h ? U[4]  : U[6];
        unsigned tA3 = h ? U[5]  : U[7];
        unsigned tB0 = h ? U[8]  : U[10];
        unsigned tB1 = h ? U[9]  : U[11];
        unsigned tB2 = h ? U[12] : U[14];
        unsigned tB3 = h ? U[13] : U[15];
        unsigned rA0 = __shfl_xor(tA0, 32);
        unsigned rA1 = __shfl_xor(tA1, 32);
        unsigned rA2 = __shfl_xor(tA2, 32);
        unsigned rA3 = __shfl_xor(tA3, 32);
        unsigned rB0 = __shfl_xor(tB0, 32);
        unsigned rB1 = __shfl_xor(tB1, 32);
        unsigned rB2 = __shfl_xor(tB2, 32);
        unsigned rB3 = __shfl_xor(tB3, 32);
        Frag p0f, p1f, p2f, p3f;
        if (h == 0) {
            p0f.u[0] = U[0];  p0f.u[1] = U[1];  p0f.u[2] = rA0;   p0f.u[3] = rA1;
            p1f.u[0] = U[4];  p1f.u[1] = U[5];  p1f.u[2] = rA2;   p1f.u[3] = rA3;
            p2f.u[0] = U[8];  p2f.u[1] = U[9];  p2f.u[2] = rB0;   p2f.u[3] = rB1;
            p3f.u[0] = U[12]; p3f.u[1] = U[13]; p3f.u[2] = rB2;   p3f.u[3] = rB3;
        } else {
            p0f.u[0] = rA0;   p0f.u[1] = rA1;   p0f.u[2] = U[2];  p0f.u[3] = U[3];
            p1f.u[0] = rA2;   p1f.u[1] = rA3;   p1f.u[2] = U[6];  p1f.u[3] = U[7];
            p2f.u[0] = rB0;   p2f.u[1] = rB1;   p2f.u[2] = U[10]; p2f.u[3] = U[11];
            p3f.u[0] = rB2;   p3f.u[1] = rB3;   p3f.u[2] = U[14]; p3f.u[3] = U[15];
        }

        // --- PV: O^T[v][q] += V^T[v][k] P[k][q], tiles A then B
#pragma unroll
        for (int tb = 0; tb < 2; ++tb) {
            const int key0 = tb ? keyB : keyA;
#pragma unroll
            for (int c = 0; c < 2; ++c) {
                const Frag& pf = tb ? (c ? p3f : p2f) : (c ? p1f : p0f);
#pragma unroll
                for (int vc = 0; vc < 2; ++vc) {
                    Frag vf;
                    const int vo = (b * 64 + vc * 32 + q) * 4096 + key0 + c * 16 + 8 * h;
                    vf.i4 = *reinterpret_cast<const v4i*>(VT + vo);
                    if (vc == 0) o0 = MFMA32(vf.b8, pf.b8, o0);
                    else         o1 = MFMA32(vf.b8, pf.b8, o1);
                }
            }
        }
    }

    // --- merge the 8 per-wave partials -> per-block partial (m*, L, unnorm O)
    if (h == 0) { sm[w][q] = m_run; sl[w][q] = l_run; }
#pragma unroll
    for (int vc = 0; vc < 2; ++vc) {
        const f32x16& a = vc ? o1 : o0;
#pragma unroll
        for (int u = 0; u < 4; ++u) {
            float4 v4 = make_float4(a[4 * u], a[4 * u + 1], a[4 * u + 2], a[4 * u + 3]);
            *reinterpret_cast<float4*>(&sO[w][q][vc * 32 + 8 * u + 4 * h]) = v4;
        }
    }
    __syncthreads();

    const int qq = tid >> 4;
    const int vb = (tid & 15) * 4;
    float mstar = sm[0][qq];
#pragma unroll
    for (int ww = 1; ww < 8; ++ww) mstar = fmaxf(mstar, sm[ww][qq]);
    float L = 0.f, acc0 = 0.f, acc1 = 0.f, acc2 = 0.f, acc3 = 0.f;
#pragma unroll
    for (int ww = 0; ww < 8; ++ww) {
        const float fw = exp2f(sm[ww][qq] - mstar);
        L += fw * sl[ww][qq];
        acc0 += fw * sO[ww][qq][vb + 0];
        acc1 += fw * sO[ww][qq][vb + 1];
        acc2 += fw * sO[ww][qq][vb + 2];
        acc3 += fw * sO[ww][qq][vb + 3];
    }
    const int row = b * 4096 + q0 + qq;
    *reinterpret_cast<float4*>(Opart + ((size_t)half * 8192 + row) * 64 + vb) =
        make_float4(acc0, acc1, acc2, acc3);
    if (vb == 0) {
        ml[((size_t)half * 8192 + row) * 2 + 0] = mstar;
        ml[((size_t)half * 8192 + row) * 2 + 1] = L;
    }
}

// ---------------- cross-block merge of the 2 key-halves ----------------
__global__ __launch_bounds__(256) void merge_kernel(
    const float* __restrict__ Opart, const float* __restrict__ ml, float* __restrict__ out)
{
    const int idx = blockIdx.x * 256 + threadIdx.x;  // 131072
    const int row = idx >> 4, vb = (idx & 15) * 4;
    const float m0 = ml[row * 2 + 0],            l0 = ml[row * 2 + 1];
    const float m1 = ml[(8192 + row) * 2 + 0],   l1 = ml[(8192 + row) * 2 + 1];
    const float ms = fmaxf(m0, m1);
    const float w0 = exp2f(m0 - ms), w1 = exp2f(m1 - ms);
    const float inv = 1.0f / (w0 * l0 + w1 * l1);
    float4 a = *reinterpret_cast<const float4*>(Opart + (size_t)row * 64 + vb);
    float4 c = *reinterpret_cast<const float4*>(Opart + (size_t)(8192 + row) * 64 + vb);
    *reinterpret_cast<float4*>(out + (size_t)row * 64 + vb) =
        make_float4((w0 * a.x + w1 * c.x) * inv, (w0 * a.y + w1 * c.y) * inv,
                    (w0 * a.z + w1 * c.z) * inv, (w0 * a.w + w1 * c.w) * inv);
}

// ---------------- launch ----------------

extern "C" void kernel_launch(void* const* d_in, const int* in_sizes, int n_in,
                              void* d_out, int out_size, void* d_ws, size_t ws_size,
                              hipStream_t stream)
{
    const float* X  = (const float*)d_in[0];
    const float* Wq = (const float*)d_in[1];
    const float* Wk = (const float*)d_in[2];
    const float* Wv = (const float*)d_in[3];
    float* out = (float*)d_out;

    // workspace layout (shorts). Opart/ml alias Xhi/Xlo (dead after proj).
    unsigned short* Xhi = (unsigned short*)d_ws;
    unsigned short* Xlo = Xhi + 4194304;   // 2*4096*512
    unsigned short* Whi = Xlo + 4194304;
    unsigned short* Wlo = Whi + 98304;     // 192*512
    unsigned short* Qhi = Wlo + 98304;
    unsigned short* Qlo = Qhi + 524288;    // 8192*64
    unsigned short* Khi = Qlo + 524288;
    unsigned short* Klo = Khi + 524288;
    unsigned short* VT  = Klo + 524288;    // [2][64][4096]
    float* Opart = (float*)Xhi;            // [2][8192][64]  (aliases Xhi/Xlo)
    float* ml    = Opart + 1048576;        // [2][8192][2]

    split_kernel<<<2048, 256, 0, stream>>>(X, Xhi, Xlo, 1048576);
    splitW_kernel<<<96, 256, 0, stream>>>(Wq, Wk, Wv, Whi, Wlo);
    proj_kernel<<<dim3(256, 6), 64, 0, stream>>>(Xhi, Xlo, Whi, Wlo, Qhi, Qlo, Khi, Klo, VT);
    attn_kernel<<<dim3(256, 2), 512, 0, stream>>>(Qhi, Qlo, Khi, Klo, VT, Opart, ml);
    merge_kernel<<<512, 256, 0, stream>>>(Opart, ml, out);
}

// Round 8
// 77.761 us; speedup vs baseline: 1.2739x; 1.2739x over previous
//
#include <hip/hip_runtime.h>
#include <hip/hip_bf16.h>

// SelfAttention: B=2, S=4096, E=512, D=64, fp32 in/out.
// R8 = R7 (verified) + ONE change: K and V stored in MFMA-fragment-packed
// layout by proj, so every attn loop load is wave-coalesced (base + lane*16B).
// R7's scattered loads (32-64 cache lines per instruction) saturated the
// per-CU L1/TA unit -- the invariant ~56-64us across R1/R4/R5/R7.
// All arithmetic is byte-identical to R7. No permlane (banned).

typedef float  f32x16 __attribute__((ext_vector_type(16)));
typedef short  v8bf   __attribute__((ext_vector_type(8)));
typedef int    v4i    __attribute__((ext_vector_type(4)));

#define MFMA32(a, b, c) __builtin_amdgcn_mfma_f32_32x32x16_bf16((a), (b), (c), 0, 0, 0)

union Frag { v4i i4; v8bf b8; unsigned u[4]; };

__device__ __forceinline__ unsigned short f2bf(float x) {  // RNE fp32->bf16
    unsigned u = __float_as_uint(x);
    return (unsigned short)((u + 0x7fffu + ((u >> 16) & 1u)) >> 16);
}
__device__ __forceinline__ float bf2f(unsigned short h) {
    return __uint_as_float(((unsigned)h) << 16);
}
__device__ __forceinline__ unsigned cvt_pk_bf16(float a, float b) {
    unsigned r;
    asm("v_cvt_pk_bf16_f32 %0, %1, %2" : "=v"(r) : "v"(a), "v"(b));
    return r;
}

// ---------------- split kernels: fp32 -> (hi, lo) bf16 ----------------

__global__ __launch_bounds__(256) void split_kernel(
    const float* __restrict__ src, unsigned short* __restrict__ hi,
    unsigned short* __restrict__ lo, int n4)
{
    int i = blockIdx.x * 256 + threadIdx.x;
    const int stride = gridDim.x * 256;
    for (; i < n4; i += stride) {
        float4 v = reinterpret_cast<const float4*>(src)[i];
        unsigned short h0 = f2bf(v.x), h1 = f2bf(v.y), h2 = f2bf(v.z), h3 = f2bf(v.w);
        unsigned short l0 = f2bf(v.x - bf2f(h0)), l1 = f2bf(v.y - bf2f(h1));
        unsigned short l2 = f2bf(v.z - bf2f(h2)), l3 = f2bf(v.w - bf2f(h3));
        reinterpret_cast<uint2*>(hi)[i] =
            make_uint2((unsigned)h0 | ((unsigned)h1 << 16), (unsigned)h2 | ((unsigned)h3 << 16));
        reinterpret_cast<uint2*>(lo)[i] =
            make_uint2((unsigned)l0 | ((unsigned)l1 << 16), (unsigned)l2 | ((unsigned)l3 << 16));
    }
}

__global__ __launch_bounds__(256) void splitW_kernel(
    const float* __restrict__ wq, const float* __restrict__ wk, const float* __restrict__ wv,
    unsigned short* __restrict__ hi, unsigned short* __restrict__ lo)
{
    int i = blockIdx.x * 256 + threadIdx.x;  // exactly 24576 threads
    int e = i * 4;
    const float* src = (e < 32768) ? wq : (e < 65536) ? wk : wv;
    int off = e & 32767;
    float4 v = *reinterpret_cast<const float4*>(src + off);
    unsigned short h0 = f2bf(v.x), h1 = f2bf(v.y), h2 = f2bf(v.z), h3 = f2bf(v.w);
    unsigned short l0 = f2bf(v.x - bf2f(h0)), l1 = f2bf(v.y - bf2f(h1));
    unsigned short l2 = f2bf(v.z - bf2f(h2)), l3 = f2bf(v.w - bf2f(h3));
    reinterpret_cast<uint2*>(hi)[i] =
        make_uint2((unsigned)h0 | ((unsigned)h1 << 16), (unsigned)h2 | ((unsigned)h3 << 16));
    reinterpret_cast<uint2*>(lo)[i] =
        make_uint2((unsigned)l0 | ((unsigned)l1 << 16), (unsigned)l2 | ((unsigned)l3 << 16));
}

// ---------------- projection: C[8192][192] = X[8192][512] @ W^T ----------------
// grid = (256 row-tiles, 6 col-groups: {Q,K,V} x {2 column halves}), 1 wave.
// Q: row-major hi/lo (unchanged). K: fragment-packed hi/lo. V: fragment-packed.
//
// Fragment layouts consumed by attn (lane l = 32*h + q, j = 0..7):
//   Kpk[b][tile][dc][l][j] = K[tile*32 + q][dc*16 + 8*h + j]
//   Vpk[b][tile][c][vc][l][j] = V[tile*32 + c*16 + 8*h + j][vc*32 + q]

__global__ __launch_bounds__(64, 1) void proj_kernel(
    const unsigned short* __restrict__ Xhi, const unsigned short* __restrict__ Xlo,
    const unsigned short* __restrict__ Whi, const unsigned short* __restrict__ Wlo,
    unsigned short* __restrict__ Qhi, unsigned short* __restrict__ Qlo,
    unsigned short* __restrict__ Khi, unsigned short* __restrict__ Klo,
    unsigned short* __restrict__ VT)
{
    __shared__ float t[32][33];
    const int l = threadIdx.x, h = l >> 5, r32 = l & 31;
    const int row0 = blockIdx.x * 32;
    const int g2 = blockIdx.y;   // 0..5
    const int g  = g2 >> 1;      // 0=Q, 1=K, 2=V
    const int ct = g2 & 1;       // 32-column group

    f32x16 a0;
#pragma unroll
    for (int r = 0; r < 16; ++r) a0[r] = 0.f;

    for (int kc = 0; kc < 32; ++kc) {
        const int k0 = kc * 16 + 8 * h;
        Frag xh, xl, b0h;
        const int xo = (row0 + r32) * 512 + k0;
        const int w0 = (g * 64 + ct * 32 + r32) * 512 + k0;
        xh.i4  = *reinterpret_cast<const v4i*>(Xhi + xo);
        b0h.i4 = *reinterpret_cast<const v4i*>(Whi + w0);
        a0 = MFMA32(xh.b8, b0h.b8, a0);
        if (g < 2) {
            Frag b0l;
            xl.i4  = *reinterpret_cast<const v4i*>(Xlo + xo);
            b0l.i4 = *reinterpret_cast<const v4i*>(Wlo + w0);
            a0 = MFMA32(xh.b8, b0l.b8, a0);
            a0 = MFMA32(xl.b8, b0h.b8, a0);
        }
    }

    const int bb = row0 >> 12;
    const int tl = (row0 & 4095) >> 5;   // tile index within batch

    if (g == 2) {
        // V fragment-packed, direct from accumulators.
        // a0[u] = V[row0 + crow][ct*32 + r32], crow = (u&3) + 4h + 8*(u>>2)
        //       -> c = u>>3, h' = (u>>2)&1, j = 4h + (u&3)
#pragma unroll
        for (int c = 0; c < 2; ++c)
#pragma unroll
            for (int hp = 0; hp < 2; ++hp) {
                unsigned p0 = (unsigned)f2bf(a0[8*c + 4*hp + 0]) |
                              ((unsigned)f2bf(a0[8*c + 4*hp + 1]) << 16);
                unsigned p1 = (unsigned)f2bf(a0[8*c + 4*hp + 2]) |
                              ((unsigned)f2bf(a0[8*c + 4*hp + 3]) << 16);
                const int off = ((((bb*128 + tl)*2 + c)*2 + ct)*64 + 32*hp + r32)*8 + 4*h;
                *reinterpret_cast<uint2*>(VT + off) = make_uint2(p0, p1);
            }
    } else {
        // transpose through LDS: t[s_local][odim_local]
#pragma unroll
        for (int u = 0; u < 16; ++u)
            t[(u & 3) + 8 * (u >> 2) + 4 * h][r32] = a0[u];
        __syncthreads();
        if (g == 0) {
            // Q row-major hi/lo (unchanged from R5)
            unsigned wh[8], wl[8];
#pragma unroll
            for (int j = 0; j < 8; ++j) {
                float x0 = t[r32][16 * h + 2 * j];
                float x1 = t[r32][16 * h + 2 * j + 1];
                unsigned short h0 = f2bf(x0), h1 = f2bf(x1);
                unsigned short l0 = f2bf(x0 - bf2f(h0)), l1 = f2bf(x1 - bf2f(h1));
                wh[j] = (unsigned)h0 | ((unsigned)h1 << 16);
                wl[j] = (unsigned)l0 | ((unsigned)l1 << 16);
            }
            const int off = (row0 + r32) * 64 + ct * 32 + 16 * h;
            *reinterpret_cast<uint4*>(Qhi + off)     = make_uint4(wh[0], wh[1], wh[2], wh[3]);
            *reinterpret_cast<uint4*>(Qhi + off + 8) = make_uint4(wh[4], wh[5], wh[6], wh[7]);
            *reinterpret_cast<uint4*>(Qlo + off)     = make_uint4(wl[0], wl[1], wl[2], wl[3]);
            *reinterpret_cast<uint4*>(Qlo + off + 8) = make_uint4(wl[4], wl[5], wl[6], wl[7]);
        } else {
            // K fragment-packed hi/lo. Thread (r32,h) holds key q'=r32;
            // dc = ct*2 + h; chunks for fragment-lane 32*hp + r32.
            const int dc = ct * 2 + h;
#pragma unroll
            for (int hp = 0; hp < 2; ++hp) {
                unsigned wh[4], wl[4];
#pragma unroll
                for (int jj = 0; jj < 4; ++jj) {
                    float x0 = t[r32][16 * h + 8 * hp + 2 * jj];
                    float x1 = t[r32][16 * h + 8 * hp + 2 * jj + 1];
                    unsigned short h0 = f2bf(x0), h1 = f2bf(x1);
                    unsigned short l0 = f2bf(x0 - bf2f(h0)), l1 = f2bf(x1 - bf2f(h1));
                    wh[jj] = (unsigned)h0 | ((unsigned)h1 << 16);
                    wl[jj] = (unsigned)l0 | ((unsigned)l1 << 16);
                }
                const int off = (((bb*128 + tl)*4 + dc)*64 + 32*hp + r32)*8;
                *reinterpret_cast<uint4*>(Khi + off) = make_uint4(wh[0], wh[1], wh[2], wh[3]);
                *reinterpret_cast<uint4*>(Klo + off) = make_uint4(wl[0], wl[1], wl[2], wl[3]);
            }
        }
    }
}

// ---------------- flash attention: 64-key iterations, packed loads ----------

__global__ __launch_bounds__(512, 2) void attn_kernel(
    const unsigned short* __restrict__ Qhi, const unsigned short* __restrict__ Qlo,
    const unsigned short* __restrict__ Khi, const unsigned short* __restrict__ Klo,
    const unsigned short* __restrict__ VT,
    float* __restrict__ Opart, float* __restrict__ ml)
{
    __shared__ float sO[8][32][68];
    __shared__ float sm[8][32];
    __shared__ float sl[8][32];

    const int tid = threadIdx.x;
    const int w = tid >> 6;
    const int l = tid & 63;
    const int h = l >> 5;
    const int q = l & 31;
    const int b  = blockIdx.x >> 7;
    const int q0 = (blockIdx.x & 127) * 32;
    const int half = blockIdx.y;

    Frag qh[4], ql[4];
#pragma unroll
    for (int dc = 0; dc < 4; ++dc) {
        const int o = (b * 4096 + q0 + q) * 64 + dc * 16 + 8 * h;
        qh[dc].i4 = *reinterpret_cast<const v4i*>(Qhi + o);
        ql[dc].i4 = *reinterpret_cast<const v4i*>(Qlo + o);
    }

    f32x16 o0, o1;
#pragma unroll
    for (int r = 0; r < 16; ++r) { o0[r] = 0.f; o1[r] = 0.f; }
    float m_run = -1e30f, l_run = 0.f;

    for (int it = 0; it < 4; ++it) {
        const int keyA = half * 2048 + (it * 16 + w) * 32;
        const int keyB = keyA + 256;
        const int tA = keyA >> 5;   // tile within batch
        const int tB = keyB >> 5;

        // --- two independent score chains (A,B), hi/lo split; coalesced loads
        f32x16 sA, sB;
#pragma unroll
        for (int r = 0; r < 16; ++r) { sA[r] = 0.f; sB[r] = 0.f; }
#pragma unroll
        for (int dc = 0; dc < 4; ++dc) {
            Frag kha, kla, khb, klb;
            const int koA = ((b * 128 + tA) * 4 + dc) * 512 + l * 8;
            const int koB = ((b * 128 + tB) * 4 + dc) * 512 + l * 8;
            kha.i4 = *reinterpret_cast<const v4i*>(Khi + koA);
            kla.i4 = *reinterpret_cast<const v4i*>(Klo + koA);
            khb.i4 = *reinterpret_cast<const v4i*>(Khi + koB);
            klb.i4 = *reinterpret_cast<const v4i*>(Klo + koB);
            sA = MFMA32(kha.b8, qh[dc].b8, sA);
            sB = MFMA32(khb.b8, qh[dc].b8, sB);
            sA = MFMA32(kha.b8, ql[dc].b8, sA);
            sB = MFMA32(khb.b8, ql[dc].b8, sB);
            sA = MFMA32(kla.b8, qh[dc].b8, sA);
            sB = MFMA32(klb.b8, qh[dc].b8, sB);
        }

        // --- joint softmax over 64 keys (base 2; logits = 8*score)
        const float cc = 11.541560327111707f;  // 8 * log2(e)
        float s2[32];
#pragma unroll
        for (int r = 0; r < 16; ++r) { s2[r] = sA[r] * cc; s2[16 + r] = sB[r] * cc; }
        float mb;
        {
            float t[8];
#pragma unroll
            for (int jj = 0; jj < 8; ++jj)
                t[jj] = fmaxf(fmaxf(s2[4 * jj], s2[4 * jj + 1]),
                              fmaxf(s2[4 * jj + 2], s2[4 * jj + 3]));
            float u0 = fmaxf(fmaxf(t[0], t[1]), fmaxf(t[2], t[3]));
            float u1 = fmaxf(fmaxf(t[4], t[5]), fmaxf(t[6], t[7]));
            mb = fmaxf(u0, u1);
        }
        mb = fmaxf(mb, __shfl_xor(mb, 32));

        const float m_new = fmaxf(m_run, mb);
        const float f = exp2f(m_run - m_new);
        float p[32];
        float ps0 = 0.f, ps1 = 0.f, ps2 = 0.f, ps3 = 0.f;
#pragma unroll
        for (int r = 0; r < 32; r += 4) {
            p[r]     = exp2f(s2[r]     - m_new); ps0 += p[r];
            p[r + 1] = exp2f(s2[r + 1] - m_new); ps1 += p[r + 1];
            p[r + 2] = exp2f(s2[r + 2] - m_new); ps2 += p[r + 2];
            p[r + 3] = exp2f(s2[r + 3] - m_new); ps3 += p[r + 3];
        }
        float ps = (ps0 + ps1) + (ps2 + ps3);
        ps += __shfl_xor(ps, 32);
        l_run = l_run * f + ps;
        m_run = m_new;
#pragma unroll
        for (int r = 0; r < 16; ++r) { o0[r] *= f; o1[r] *= f; }

        // --- P (C layout, k = (r&3)+8*(r>>2)+4h) -> bf16 B-frags, per tile
        unsigned U[16];
#pragma unroll
        for (int j = 0; j < 8; ++j) {
            U[j]     = cvt_pk_bf16(p[2 * j],      p[2 * j + 1]);
            U[8 + j] = cvt_pk_bf16(p[16 + 2 * j], p[16 + 2 * j + 1]);
        }
        unsigned tA0 = h ? U[0]  : U[2];
        unsigned tA1 = h ? U[1]  : U[3];
        unsigned tA2 = h ? U[4]  : U[6];
        unsigned tA3 = h ? U[5]  : U[7];
        unsigned tB0 = h ? U[8]  : U[10];
        unsigned tB1 = h ? U[9]  : U[11];
        unsigned tB2 = h ? U[12] : U[14];
        unsigned tB3 = h ? U[13] : U[15];
        unsigned rA0 = __shfl_xor(tA0, 32);
        unsigned rA1 = __shfl_xor(tA1, 32);
        unsigned rA2 = __shfl_xor(tA2, 32);
        unsigned rA3 = __shfl_xor(tA3, 32);
        unsigned rB0 = __shfl_xor(tB0, 32);
        unsigned rB1 = __shfl_xor(tB1, 32);
        unsigned rB2 = __shfl_xor(tB2, 32);
        unsigned rB3 = __shfl_xor(tB3, 32);
        Frag p0f, p1f, p2f, p3f;
        if (h == 0) {
            p0f.u[0] = U[0];  p0f.u[1] = U[1];  p0f.u[2] = rA0;   p0f.u[3] = rA1;
            p1f.u[0] = U[4];  p1f.u[1] = U[5];  p1f.u[2] = rA2;   p1f.u[3] = rA3;
            p2f.u[0] = U[8];  p2f.u[1] = U[9];  p2f.u[2] = rB0;   p2f.u[3] = rB1;
            p3f.u[0] = U[12]; p3f.u[1] = U[13]; p3f.u[2] = rB2;   p3f.u[3] = rB3;
        } else {
            p0f.u[0] = rA0;   p0f.u[1] = rA1;   p0f.u[2] = U[2];  p0f.u[3] = U[3];
            p1f.u[0] = rA2;   p1f.u[1] = rA3;   p1f.u[2] = U[6];  p1f.u[3] = U[7];
            p2f.u[0] = rB0;   p2f.u[1] = rB1;   p2f.u[2] = U[10]; p2f.u[3] = U[11];
            p3f.u[0] = rB2;   p3f.u[1] = rB3;   p3f.u[2] = U[14]; p3f.u[3] = U[15];
        }

        // --- PV: O^T[v][q] += V^T[v][k] P[k][q]; packed coalesced V loads
#pragma unroll
        for (int tb = 0; tb < 2; ++tb) {
            const int tt = tb ? tB : tA;
#pragma unroll
            for (int c = 0; c < 2; ++c) {
                const Frag& pf = tb ? (c ? p3f : p2f) : (c ? p1f : p0f);
#pragma unroll
                for (int vc = 0; vc < 2; ++vc) {
                    Frag vf;
                    const int vo = (((b * 128 + tt) * 2 + c) * 2 + vc) * 512 + l * 8;
                    vf.i4 = *reinterpret_cast<const v4i*>(VT + vo);
                    if (vc == 0) o0 = MFMA32(vf.b8, pf.b8, o0);
                    else         o1 = MFMA32(vf.b8, pf.b8, o1);
                }
            }
        }
    }

    // --- merge the 8 per-wave partials -> per-block partial (m*, L, unnorm O)
    if (h == 0) { sm[w][q] = m_run; sl[w][q] = l_run; }
#pragma unroll
    for (int vc = 0; vc < 2; ++vc) {
        const f32x16& a = vc ? o1 : o0;
#pragma unroll
        for (int u = 0; u < 4; ++u) {
            float4 v4 = make_float4(a[4 * u], a[4 * u + 1], a[4 * u + 2], a[4 * u + 3]);
            *reinterpret_cast<float4*>(&sO[w][q][vc * 32 + 8 * u + 4 * h]) = v4;
        }
    }
    __syncthreads();

    const int qq = tid >> 4;
    const int vb = (tid & 15) * 4;
    float mstar = sm[0][qq];
#pragma unroll
    for (int ww = 1; ww < 8; ++ww) mstar = fmaxf(mstar, sm[ww][qq]);
    float L = 0.f, acc0 = 0.f, acc1 = 0.f, acc2 = 0.f, acc3 = 0.f;
#pragma unroll
    for (int ww = 0; ww < 8; ++ww) {
        const float fw = exp2f(sm[ww][qq] - mstar);
        L += fw * sl[ww][qq];
        acc0 += fw * sO[ww][qq][vb + 0];
        acc1 += fw * sO[ww][qq][vb + 1];
        acc2 += fw * sO[ww][qq][vb + 2];
        acc3 += fw * sO[ww][qq][vb + 3];
    }
    const int row = b * 4096 + q0 + qq;
    *reinterpret_cast<float4*>(Opart + ((size_t)half * 8192 + row) * 64 + vb) =
        make_float4(acc0, acc1, acc2, acc3);
    if (vb == 0) {
        ml[((size_t)half * 8192 + row) * 2 + 0] = mstar;
        ml[((size_t)half * 8192 + row) * 2 + 1] = L;
    }
}

// ---------------- cross-block merge of the 2 key-halves ----------------
__global__ __launch_bounds__(256) void merge_kernel(
    const float* __restrict__ Opart, const float* __restrict__ ml, float* __restrict__ out)
{
    const int idx = blockIdx.x * 256 + threadIdx.x;  // 131072
    const int row = idx >> 4, vb = (idx & 15) * 4;
    const float m0 = ml[row * 2 + 0],            l0 = ml[row * 2 + 1];
    const float m1 = ml[(8192 + row) * 2 + 0],   l1 = ml[(8192 + row) * 2 + 1];
    const float ms = fmaxf(m0, m1);
    const float w0 = exp2f(m0 - ms), w1 = exp2f(m1 - ms);
    const float inv = 1.0f / (w0 * l0 + w1 * l1);
    float4 a = *reinterpret_cast<const float4*>(Opart + (size_t)row * 64 + vb);
    float4 c = *reinterpret_cast<const float4*>(Opart + (size_t)(8192 + row) * 64 + vb);
    *reinterpret_cast<float4*>(out + (size_t)row * 64 + vb) =
        make_float4((w0 * a.x + w1 * c.x) * inv, (w0 * a.y + w1 * c.y) * inv,
                    (w0 * a.z + w1 * c.z) * inv, (w0 * a.w + w1 * c.w) * inv);
}

// ---------------- launch ----------------

extern "C" void kernel_launch(void* const* d_in, const int* in_sizes, int n_in,
                              void* d_out, int out_size, void* d_ws, size_t ws_size,
                              hipStream_t stream)
{
    const float* X  = (const float*)d_in[0];
    const float* Wq = (const float*)d_in[1];
    const float* Wk = (const float*)d_in[2];
    const float* Wv = (const float*)d_in[3];
    float* out = (float*)d_out;

    // workspace layout (shorts). Opart/ml alias Xhi/Xlo (dead after proj).
    // Khi/Klo slots now hold Kpk (same size); VT slot holds Vpk (same size).
    unsigned short* Xhi = (unsigned short*)d_ws;
    unsigned short* Xlo = Xhi + 4194304;   // 2*4096*512
    unsigned short* Whi = Xlo + 4194304;
    unsigned short* Wlo = Whi + 98304;     // 192*512
    unsigned short* Qhi = Wlo + 98304;
    unsigned short* Qlo = Qhi + 524288;    // 8192*64
    unsigned short* Khi = Qlo + 524288;    // Kpk hi: [2][128][4][64][8]
    unsigned short* Klo = Khi + 524288;    // Kpk lo
    unsigned short* VT  = Klo + 524288;    // Vpk: [2][128][2][2][64][8]
    float* Opart = (float*)Xhi;            // [2][8192][64]  (aliases Xhi/Xlo)
    float* ml    = Opart + 1048576;        // [2][8192][2]

    split_kernel<<<2048, 256, 0, stream>>>(X, Xhi, Xlo, 1048576);
    splitW_kernel<<<96, 256, 0, stream>>>(Wq, Wk, Wv, Whi, Wlo);
    proj_kernel<<<dim3(256, 6), 64, 0, stream>>>(Xhi, Xlo, Whi, Wlo, Qhi, Qlo, Khi, Klo, VT);
    attn_kernel<<<dim3(256, 2), 512, 0, stream>>>(Qhi, Qlo, Khi, Klo, VT, Opart, ml);
    merge_kernel<<<512, 256, 0, stream>>>(Opart, ml, out);
}

// Round 9
// 69.674 us; speedup vs baseline: 1.4218x; 1.1161x over previous
//
#include <hip/hip_runtime.h>
#include <hip/hip_bf16.h>

// SelfAttention: B=2, S=4096, E=512, D=64, fp32 in/out.
// R9 = R8 (verified) + ONE change: split_kernel deleted; proj fused to
// 6 waves/block staging the X tile ONCE in LDS (hi/lo bf16 fragment chunks,
// conversion bit-identical to the old split_kernel). attn/splitW/merge are
// byte-identical to R8. No permlane (banned).

typedef float  f32x16 __attribute__((ext_vector_type(16)));
typedef short  v8bf   __attribute__((ext_vector_type(8)));
typedef int    v4i    __attribute__((ext_vector_type(4)));

#define MFMA32(a, b, c) __builtin_amdgcn_mfma_f32_32x32x16_bf16((a), (b), (c), 0, 0, 0)

union Frag { v4i i4; v8bf b8; unsigned u[4]; };

__device__ __forceinline__ unsigned short f2bf(float x) {  // RNE fp32->bf16
    unsigned u = __float_as_uint(x);
    return (unsigned short)((u + 0x7fffu + ((u >> 16) & 1u)) >> 16);
}
__device__ __forceinline__ float bf2f(unsigned short h) {
    return __uint_as_float(((unsigned)h) << 16);
}
__device__ __forceinline__ unsigned cvt_pk_bf16(float a, float b) {
    unsigned r;
    asm("v_cvt_pk_bf16_f32 %0, %1, %2" : "=v"(r) : "v"(a), "v"(b));
    return r;
}

// ---------------- W split: [Wq;Wk;Wv] -> hi/lo bf16 (unchanged) ----------------

__global__ __launch_bounds__(256) void splitW_kernel(
    const float* __restrict__ wq, const float* __restrict__ wk, const float* __restrict__ wv,
    unsigned short* __restrict__ hi, unsigned short* __restrict__ lo)
{
    int i = blockIdx.x * 256 + threadIdx.x;  // exactly 24576 threads
    int e = i * 4;
    const float* src = (e < 32768) ? wq : (e < 65536) ? wk : wv;
    int off = e & 32767;
    float4 v = *reinterpret_cast<const float4*>(src + off);
    unsigned short h0 = f2bf(v.x), h1 = f2bf(v.y), h2 = f2bf(v.z), h3 = f2bf(v.w);
    unsigned short l0 = f2bf(v.x - bf2f(h0)), l1 = f2bf(v.y - bf2f(h1));
    unsigned short l2 = f2bf(v.z - bf2f(h2)), l3 = f2bf(v.w - bf2f(h3));
    reinterpret_cast<uint2*>(hi)[i] =
        make_uint2((unsigned)h0 | ((unsigned)h1 << 16), (unsigned)h2 | ((unsigned)h3 << 16));
    reinterpret_cast<uint2*>(lo)[i] =
        make_uint2((unsigned)l0 | ((unsigned)l1 << 16), (unsigned)l2 | ((unsigned)l3 << 16));
}

// ---------------- fused projection ----------------
// grid = 256 row-tiles (32 rows), block = 384 = 6 waves, wave w -> (g, ct):
// g = w>>1 in {Q,K,V}, ct = w&1 column half. Phase 1: stage X fp32 -> hi/lo
// bf16 fragment chunks in LDS (once). Phase 2: per-wave MFMA loop (inputs
// bit-identical to R8's global Xhi/Xlo reads). Epilogues verbatim from R8.
//
// LDS chunk layout: chunk (row, cc) (cc = e0/8, 64 chunks/row) stored at
// index row*64 + (cc ^ (row & 7))  [XOR swizzle: conflict-free writes,
// 4-way reads]. Fragment for (kc, lane l): row = l&31, cc = kc*2 + (l>>5).

__global__ __launch_bounds__(384, 1) void proj_kernel(
    const float* __restrict__ X,
    const unsigned short* __restrict__ Whi, const unsigned short* __restrict__ Wlo,
    unsigned short* __restrict__ Qhi, unsigned short* __restrict__ Qlo,
    unsigned short* __restrict__ Khi, unsigned short* __restrict__ Klo,
    unsigned short* __restrict__ VT)
{
    __shared__ uint4 XhiS[2048];   // 32 KB
    __shared__ uint4 XloS[2048];   // 32 KB
    __shared__ float t4[4][32][33];

    const int tid = threadIdx.x;
    const int w = tid >> 6;        // 0..5
    const int l = tid & 63, h = l >> 5, r32 = l & 31;
    const int row0 = blockIdx.x * 32;
    const int g = w >> 1, ct = w & 1;

    // --- phase 1: stage X tile (rows row0..row0+31), hi/lo split in-register
    for (int id = tid; id < 2048; id += 384) {
        const int row = id >> 6, cc = id & 63;
        const float* xp = X + (row0 + row) * 512 + cc * 8;
        float4 va = *reinterpret_cast<const float4*>(xp);
        float4 vb = *reinterpret_cast<const float4*>(xp + 4);
        float xs[8] = {va.x, va.y, va.z, va.w, vb.x, vb.y, vb.z, vb.w};
        unsigned uh[4], ul[4];
#pragma unroll
        for (int j = 0; j < 4; ++j) {
            unsigned short h0 = f2bf(xs[2 * j]),            h1 = f2bf(xs[2 * j + 1]);
            unsigned short l0 = f2bf(xs[2 * j] - bf2f(h0)), l1 = f2bf(xs[2 * j + 1] - bf2f(h1));
            uh[j] = (unsigned)h0 | ((unsigned)h1 << 16);
            ul[j] = (unsigned)l0 | ((unsigned)l1 << 16);
        }
        const int idx = row * 64 + (cc ^ (row & 7));
        XhiS[idx] = make_uint4(uh[0], uh[1], uh[2], uh[3]);
        XloS[idx] = make_uint4(ul[0], ul[1], ul[2], ul[3]);
    }
    __syncthreads();

    // --- phase 2: MFMA loop (same math as R8, X frags from LDS)
    f32x16 a0;
#pragma unroll
    for (int r = 0; r < 16; ++r) a0[r] = 0.f;

    for (int kc = 0; kc < 32; ++kc) {
        const int k0 = kc * 16 + 8 * h;
        const int idx = r32 * 64 + ((kc * 2 + h) ^ (r32 & 7));
        Frag xh, b0h;
        xh.i4 = *reinterpret_cast<const v4i*>(&XhiS[idx]);
        const int w0 = (g * 64 + ct * 32 + r32) * 512 + k0;
        b0h.i4 = *reinterpret_cast<const v4i*>(Whi + w0);
        a0 = MFMA32(xh.b8, b0h.b8, a0);
        if (g < 2) {
            Frag xl, b0l;
            xl.i4 = *reinterpret_cast<const v4i*>(&XloS[idx]);
            b0l.i4 = *reinterpret_cast<const v4i*>(Wlo + w0);
            a0 = MFMA32(xh.b8, b0l.b8, a0);
            a0 = MFMA32(xl.b8, b0h.b8, a0);
        }
    }

    const int bb = row0 >> 12;
    const int tl = (row0 & 4095) >> 5;   // tile index within batch

    // --- epilogues (R8 verbatim; t buffer per wave, barrier is uniform)
    if (g < 2) {
#pragma unroll
        for (int u = 0; u < 16; ++u)
            t4[w][(u & 3) + 8 * (u >> 2) + 4 * h][r32] = a0[u];
    }
    __syncthreads();

    if (g == 2) {
        // V fragment-packed, direct from accumulators.
#pragma unroll
        for (int c = 0; c < 2; ++c)
#pragma unroll
            for (int hp = 0; hp < 2; ++hp) {
                unsigned p0 = (unsigned)f2bf(a0[8*c + 4*hp + 0]) |
                              ((unsigned)f2bf(a0[8*c + 4*hp + 1]) << 16);
                unsigned p1 = (unsigned)f2bf(a0[8*c + 4*hp + 2]) |
                              ((unsigned)f2bf(a0[8*c + 4*hp + 3]) << 16);
                const int off = ((((bb*128 + tl)*2 + c)*2 + ct)*64 + 32*hp + r32)*8 + 4*h;
                *reinterpret_cast<uint2*>(VT + off) = make_uint2(p0, p1);
            }
    } else if (g == 0) {
        // Q row-major hi/lo
        unsigned wh[8], wl[8];
#pragma unroll
        for (int j = 0; j < 8; ++j) {
            float x0 = t4[w][r32][16 * h + 2 * j];
            float x1 = t4[w][r32][16 * h + 2 * j + 1];
            unsigned short h0 = f2bf(x0), h1 = f2bf(x1);
            unsigned short l0 = f2bf(x0 - bf2f(h0)), l1 = f2bf(x1 - bf2f(h1));
            wh[j] = (unsigned)h0 | ((unsigned)h1 << 16);
            wl[j] = (unsigned)l0 | ((unsigned)l1 << 16);
        }
        const int off = (row0 + r32) * 64 + ct * 32 + 16 * h;
        *reinterpret_cast<uint4*>(Qhi + off)     = make_uint4(wh[0], wh[1], wh[2], wh[3]);
        *reinterpret_cast<uint4*>(Qhi + off + 8) = make_uint4(wh[4], wh[5], wh[6], wh[7]);
        *reinterpret_cast<uint4*>(Qlo + off)     = make_uint4(wl[0], wl[1], wl[2], wl[3]);
        *reinterpret_cast<uint4*>(Qlo + off + 8) = make_uint4(wl[4], wl[5], wl[6], wl[7]);
    } else {
        // K fragment-packed hi/lo
        const int dc = ct * 2 + h;
#pragma unroll
        for (int hp = 0; hp < 2; ++hp) {
            unsigned wh[4], wl[4];
#pragma unroll
            for (int jj = 0; jj < 4; ++jj) {
                float x0 = t4[w][r32][16 * h + 8 * hp + 2 * jj];
                float x1 = t4[w][r32][16 * h + 8 * hp + 2 * jj + 1];
                unsigned short h0 = f2bf(x0), h1 = f2bf(x1);
                unsigned short l0 = f2bf(x0 - bf2f(h0)), l1 = f2bf(x1 - bf2f(h1));
                wh[jj] = (unsigned)h0 | ((unsigned)h1 << 16);
                wl[jj] = (unsigned)l0 | ((unsigned)l1 << 16);
            }
            const int off = (((bb*128 + tl)*4 + dc)*64 + 32*hp + r32)*8;
            *reinterpret_cast<uint4*>(Khi + off) = make_uint4(wh[0], wh[1], wh[2], wh[3]);
            *reinterpret_cast<uint4*>(Klo + off) = make_uint4(wl[0], wl[1], wl[2], wl[3]);
        }
    }
}

// ---------------- flash attention (byte-identical to R8) ----------

__global__ __launch_bounds__(512, 2) void attn_kernel(
    const unsigned short* __restrict__ Qhi, const unsigned short* __restrict__ Qlo,
    const unsigned short* __restrict__ Khi, const unsigned short* __restrict__ Klo,
    const unsigned short* __restrict__ VT,
    float* __restrict__ Opart, float* __restrict__ ml)
{
    __shared__ float sO[8][32][68];
    __shared__ float sm[8][32];
    __shared__ float sl[8][32];

    const int tid = threadIdx.x;
    const int w = tid >> 6;
    const int l = tid & 63;
    const int h = l >> 5;
    const int q = l & 31;
    const int b  = blockIdx.x >> 7;
    const int q0 = (blockIdx.x & 127) * 32;
    const int half = blockIdx.y;

    Frag qh[4], ql[4];
#pragma unroll
    for (int dc = 0; dc < 4; ++dc) {
        const int o = (b * 4096 + q0 + q) * 64 + dc * 16 + 8 * h;
        qh[dc].i4 = *reinterpret_cast<const v4i*>(Qhi + o);
        ql[dc].i4 = *reinterpret_cast<const v4i*>(Qlo + o);
    }

    f32x16 o0, o1;
#pragma unroll
    for (int r = 0; r < 16; ++r) { o0[r] = 0.f; o1[r] = 0.f; }
    float m_run = -1e30f, l_run = 0.f;

    for (int it = 0; it < 4; ++it) {
        const int keyA = half * 2048 + (it * 16 + w) * 32;
        const int keyB = keyA + 256;
        const int tA = keyA >> 5;
        const int tB = keyB >> 5;

        f32x16 sA, sB;
#pragma unroll
        for (int r = 0; r < 16; ++r) { sA[r] = 0.f; sB[r] = 0.f; }
#pragma unroll
        for (int dc = 0; dc < 4; ++dc) {
            Frag kha, kla, khb, klb;
            const int koA = ((b * 128 + tA) * 4 + dc) * 512 + l * 8;
            const int koB = ((b * 128 + tB) * 4 + dc) * 512 + l * 8;
            kha.i4 = *reinterpret_cast<const v4i*>(Khi + koA);
            kla.i4 = *reinterpret_cast<const v4i*>(Klo + koA);
            khb.i4 = *reinterpret_cast<const v4i*>(Khi + koB);
            klb.i4 = *reinterpret_cast<const v4i*>(Klo + koB);
            sA = MFMA32(kha.b8, qh[dc].b8, sA);
            sB = MFMA32(khb.b8, qh[dc].b8, sB);
            sA = MFMA32(kha.b8, ql[dc].b8, sA);
            sB = MFMA32(khb.b8, ql[dc].b8, sB);
            sA = MFMA32(kla.b8, qh[dc].b8, sA);
            sB = MFMA32(klb.b8, qh[dc].b8, sB);
        }

        const float cc = 11.541560327111707f;  // 8 * log2(e)
        float s2[32];
#pragma unroll
        for (int r = 0; r < 16; ++r) { s2[r] = sA[r] * cc; s2[16 + r] = sB[r] * cc; }
        float mb;
        {
            float t[8];
#pragma unroll
            for (int jj = 0; jj < 8; ++jj)
                t[jj] = fmaxf(fmaxf(s2[4 * jj], s2[4 * jj + 1]),
                              fmaxf(s2[4 * jj + 2], s2[4 * jj + 3]));
            float u0 = fmaxf(fmaxf(t[0], t[1]), fmaxf(t[2], t[3]));
            float u1 = fmaxf(fmaxf(t[4], t[5]), fmaxf(t[6], t[7]));
            mb = fmaxf(u0, u1);
        }
        mb = fmaxf(mb, __shfl_xor(mb, 32));

        const float m_new = fmaxf(m_run, mb);
        const float f = exp2f(m_run - m_new);
        float p[32];
        float ps0 = 0.f, ps1 = 0.f, ps2 = 0.f, ps3 = 0.f;
#pragma unroll
        for (int r = 0; r < 32; r += 4) {
            p[r]     = exp2f(s2[r]     - m_new); ps0 += p[r];
            p[r + 1] = exp2f(s2[r + 1] - m_new); ps1 += p[r + 1];
            p[r + 2] = exp2f(s2[r + 2] - m_new); ps2 += p[r + 2];
            p[r + 3] = exp2f(s2[r + 3] - m_new); ps3 += p[r + 3];
        }
        float ps = (ps0 + ps1) + (ps2 + ps3);
        ps += __shfl_xor(ps, 32);
        l_run = l_run * f + ps;
        m_run = m_new;
#pragma unroll
        for (int r = 0; r < 16; ++r) { o0[r] *= f; o1[r] *= f; }

        unsigned U[16];
#pragma unroll
        for (int j = 0; j < 8; ++j) {
            U[j]     = cvt_pk_bf16(p[2 * j],      p[2 * j + 1]);
            U[8 + j] = cvt_pk_bf16(p[16 + 2 * j], p[16 + 2 * j + 1]);
        }
        unsigned tA0 = h ? U[0]  : U[2];
        unsigned tA1 = h ? U[1]  : U[3];
        unsigned tA2 = h ? U[4]  : U[6];
        unsigned tA3 = h ? U[5]  : U[7];
        unsigned tB0 = h ? U[8]  : U[10];
        unsigned tB1 = h ? U[9]  : U[11];
        unsigned tB2 = h ? U[12] : U[14];
        unsigned tB3 = h ? U[13] : U[15];
        unsigned rA0 = __shfl_xor(tA0, 32);
        unsigned rA1 = __shfl_xor(tA1, 32);
        unsigned rA2 = __shfl_xor(tA2, 32);
        unsigned rA3 = __shfl_xor(tA3, 32);
        unsigned rB0 = __shfl_xor(tB0, 32);
        unsigned rB1 = __shfl_xor(tB1, 32);
        unsigned rB2 = __shfl_xor(tB2, 32);
        unsigned rB3 = __shfl_xor(tB3, 32);
        Frag p0f, p1f, p2f, p3f;
        if (h == 0) {
            p0f.u[0] = U[0];  p0f.u[1] = U[1];  p0f.u[2] = rA0;   p0f.u[3] = rA1;
            p1f.u[0] = U[4];  p1f.u[1] = U[5];  p1f.u[2] = rA2;   p1f.u[3] = rA3;
            p2f.u[0] = U[8];  p2f.u[1] = U[9];  p2f.u[2] = rB0;   p2f.u[3] = rB1;
            p3f.u[0] = U[12]; p3f.u[1] = U[13]; p3f.u[2] = rB2;   p3f.u[3] = rB3;
        } else {
            p0f.u[0] = rA0;   p0f.u[1] = rA1;   p0f.u[2] = U[2];  p0f.u[3] = U[3];
            p1f.u[0] = rA2;   p1f.u[1] = rA3;   p1f.u[2] = U[6];  p1f.u[3] = U[7];
            p2f.u[0] = rB0;   p2f.u[1] = rB1;   p2f.u[2] = U[10]; p2f.u[3] = U[11];
            p3f.u[0] = rB2;   p3f.u[1] = rB3;   p3f.u[2] = U[14]; p3f.u[3] = U[15];
        }

#pragma unroll
        for (int tb = 0; tb < 2; ++tb) {
            const int tt = tb ? tB : tA;
#pragma unroll
            for (int c = 0; c < 2; ++c) {
                const Frag& pf = tb ? (c ? p3f : p2f) : (c ? p1f : p0f);
#pragma unroll
                for (int vc = 0; vc < 2; ++vc) {
                    Frag vf;
                    const int vo = (((b * 128 + tt) * 2 + c) * 2 + vc) * 512 + l * 8;
                    vf.i4 = *reinterpret_cast<const v4i*>(VT + vo);
                    if (vc == 0) o0 = MFMA32(vf.b8, pf.b8, o0);
                    else         o1 = MFMA32(vf.b8, pf.b8, o1);
                }
            }
        }
    }

    if (h == 0) { sm[w][q] = m_run; sl[w][q] = l_run; }
#pragma unroll
    for (int vc = 0; vc < 2; ++vc) {
        const f32x16& a = vc ? o1 : o0;
#pragma unroll
        for (int u = 0; u < 4; ++u) {
            float4 v4 = make_float4(a[4 * u], a[4 * u + 1], a[4 * u + 2], a[4 * u + 3]);
            *reinterpret_cast<float4*>(&sO[w][q][vc * 32 + 8 * u + 4 * h]) = v4;
        }
    }
    __syncthreads();

    const int qq = tid >> 4;
    const int vb = (tid & 15) * 4;
    float mstar = sm[0][qq];
#pragma unroll
    for (int ww = 1; ww < 8; ++ww) mstar = fmaxf(mstar, sm[ww][qq]);
    float L = 0.f, acc0 = 0.f, acc1 = 0.f, acc2 = 0.f, acc3 = 0.f;
#pragma unroll
    for (int ww = 0; ww < 8; ++ww) {
        const float fw = exp2f(sm[ww][qq] - mstar);
        L += fw * sl[ww][qq];
        acc0 += fw * sO[ww][qq][vb + 0];
        acc1 += fw * sO[ww][qq][vb + 1];
        acc2 += fw * sO[ww][qq][vb + 2];
        acc3 += fw * sO[ww][qq][vb + 3];
    }
    const int row = b * 4096 + q0 + qq;
    *reinterpret_cast<float4*>(Opart + ((size_t)half * 8192 + row) * 64 + vb) =
        make_float4(acc0, acc1, acc2, acc3);
    if (vb == 0) {
        ml[((size_t)half * 8192 + row) * 2 + 0] = mstar;
        ml[((size_t)half * 8192 + row) * 2 + 1] = L;
    }
}

// ---------------- cross-block merge of the 2 key-halves ----------------
__global__ __launch_bounds__(256) void merge_kernel(
    const float* __restrict__ Opart, const float* __restrict__ ml, float* __restrict__ out)
{
    const int idx = blockIdx.x * 256 + threadIdx.x;  // 131072
    const int row = idx >> 4, vb = (idx & 15) * 4;
    const float m0 = ml[row * 2 + 0],            l0 = ml[row * 2 + 1];
    const float m1 = ml[(8192 + row) * 2 + 0],   l1 = ml[(8192 + row) * 2 + 1];
    const float ms = fmaxf(m0, m1);
    const float w0 = exp2f(m0 - ms), w1 = exp2f(m1 - ms);
    const float inv = 1.0f / (w0 * l0 + w1 * l1);
    float4 a = *reinterpret_cast<const float4*>(Opart + (size_t)row * 64 + vb);
    float4 c = *reinterpret_cast<const float4*>(Opart + (size_t)(8192 + row) * 64 + vb);
    *reinterpret_cast<float4*>(out + (size_t)row * 64 + vb) =
        make_float4((w0 * a.x + w1 * c.x) * inv, (w0 * a.y + w1 * c.y) * inv,
                    (w0 * a.z + w1 * c.z) * inv, (w0 * a.w + w1 * c.w) * inv);
}

// ---------------- launch ----------------

extern "C" void kernel_launch(void* const* d_in, const int* in_sizes, int n_in,
                              void* d_out, int out_size, void* d_ws, size_t ws_size,
                              hipStream_t stream)
{
    const float* X  = (const float*)d_in[0];
    const float* Wq = (const float*)d_in[1];
    const float* Wk = (const float*)d_in[2];
    const float* Wv = (const float*)d_in[3];
    float* out = (float*)d_out;

    // workspace layout (shorts then floats), ~9.8 MB total.
    unsigned short* Whi = (unsigned short*)d_ws;
    unsigned short* Wlo = Whi + 98304;     // 192*512
    unsigned short* Qhi = Wlo + 98304;
    unsigned short* Qlo = Qhi + 524288;    // 8192*64
    unsigned short* Khi = Qlo + 524288;    // Kpk hi: [2][128][4][64][8]
    unsigned short* Klo = Khi + 524288;    // Kpk lo
    unsigned short* VT  = Klo + 524288;    // Vpk: [2][128][2][2][64][8]
    float* Opart = (float*)(VT + 524288);  // [2][8192][64]
    float* ml    = Opart + 1048576;        // [2][8192][2]

    splitW_kernel<<<96, 256, 0, stream>>>(Wq, Wk, Wv, Whi, Wlo);
    proj_kernel<<<256, 384, 0, stream>>>(X, Whi, Wlo, Qhi, Qlo, Khi, Klo, VT);
    attn_kernel<<<dim3(256, 2), 512, 0, stream>>>(Qhi, Qlo, Khi, Klo, VT, Opart, ml);
    merge_kernel<<<512, 256, 0, stream>>>(Opart, ml, out);
}